// Round 15
// baseline (332.130 us; speedup 1.0000x reference)
//
#include <hip/hip_runtime.h>
#include <hip/hip_bf16.h>

typedef unsigned int uint32;
typedef float floatx2 __attribute__((ext_vector_type(2)));
typedef __attribute__((ext_vector_type(8))) short bf16x8;
typedef __attribute__((ext_vector_type(4))) float f32x4;

#define CHUNK 4096   // R13: 391 blocks for bhist/bscatter

// ============ bucketed CSR build (dst>>8 buckets, LDS-atomic sort) ============
// NOTE (R12 lesson): do NOT replace with a direct global-atomic scatter --
// random 4B stores write-allocate full 64B lines (~102 MB write traffic).
// The bucket structure keeps ssrc/ebuf writes in 64KB L2-resident windows.

__global__ __launch_bounds__(256) void k_bhist(const int* __restrict__ dst,
                                               int* __restrict__ bcnt,
                                               int E, int NBUCK, int NCH) {
    __shared__ int h[512];
    int c = blockIdx.x, tid = threadIdx.x;
    for (int i = tid; i < NBUCK; i += 256) h[i] = 0;
    __syncthreads();
    int base = c * CHUNK;
#pragma unroll
    for (int k = 0; k < CHUNK / 256; ++k) {
        int e = base + k * 256 + tid;
        if (e < E) atomicAdd(&h[dst[e] >> 8], 1);
    }
    __syncthreads();
    for (int i = tid; i < NBUCK; i += 256) bcnt[(size_t)i * NCH + c] = h[i];
}

// scans NCH (<=512) chunk counts per bucket
__global__ __launch_bounds__(512) void k_bscan1(const int* __restrict__ bcnt,
                                                int* __restrict__ bofs,
                                                int* __restrict__ btot, int NCH) {
    __shared__ int tmp[512];
    int b = blockIdx.x, t = threadIdx.x;
    int v = (t < NCH) ? bcnt[(size_t)b * NCH + t] : 0;
    tmp[t] = v;
    __syncthreads();
    for (int off = 1; off < 512; off <<= 1) {
        int u = (t >= off) ? tmp[t - off] : 0;
        __syncthreads();
        tmp[t] += u;
        __syncthreads();
    }
    if (t < NCH) bofs[(size_t)b * NCH + t] = tmp[t] - v;
    if (t == 511) btot[b] = tmp[511];
}

// also zeroes the fp8 sentinel rows (replaces two hipMemsetAsync dispatches)
__global__ __launch_bounds__(512) void k_bscan2(const int* __restrict__ btot,
                                                int* __restrict__ bbase, int nb,
                                                uint32* __restrict__ sent0,
                                                uint32* __restrict__ sent1) {
    __shared__ int tmp[512];
    int t = threadIdx.x;
    if (t < 8) { sent0[t] = 0; sent1[t] = 0; }
    int v = (t < nb) ? btot[t] : 0;
    tmp[t] = v;
    __syncthreads();
    for (int off = 1; off < 512; off <<= 1) {
        int u = (t >= off) ? tmp[t - off] : 0;
        __syncthreads();
        tmp[t] += u;
        __syncthreads();
    }
    if (t < nb) bbase[t] = tmp[t] - v;
    if (t == nb - 1) bbase[nb] = tmp[t];
}

__global__ __launch_bounds__(256) void k_bscatter(const int* __restrict__ ei,
                                                  const int* __restrict__ bbase,
                                                  const int* __restrict__ bofs,
                                                  uint32* __restrict__ ebuf,
                                                  int E, int NBUCK, int NCH) {
    __shared__ int cur[512];
    int c = blockIdx.x, tid = threadIdx.x;
    for (int i = tid; i < NBUCK; i += 256)
        cur[i] = bbase[i] + bofs[(size_t)i * NCH + c];
    __syncthreads();
    int base = c * CHUNK;
#pragma unroll
    for (int k = 0; k < CHUNK / 256; ++k) {
        int e = base + k * 256 + tid;
        if (e < E) {
            int s = ei[e];
            int d = ei[E + e];
            int p = atomicAdd(&cur[d >> 8], 1);
            ebuf[p] = (uint32)s | ((uint32)(d & 255) << 20);
        }
    }
}

// builds CSR rows AND a per-256-window degree-sorted permutation (R14):
// perm[b*256 .. b*256+255] = this window's nodes ordered by ascending degree.
// k_agg's 16-dst groups then have near-equal degrees -> maxd ~= deg
// (kills the ~70% wasted gather slots from max-of-16-Poisson straggling).

__global__ __launch_bounds__(256) void k_bsort(const uint32* __restrict__ ebuf,
                                               const int* __restrict__ bbase,
                                               int* __restrict__ ssrc,
                                               int2* __restrict__ rc,
                                               float* __restrict__ dinv,
                                               int* __restrict__ perm, int N) {
    __shared__ int h[256];
    __shared__ int sc[256];
    __shared__ int cur[256];
    int b = blockIdx.x, tid = threadIdx.x;
    int beg = bbase[b], end = bbase[b + 1];
    h[tid] = 0;
    __syncthreads();
    for (int j = beg + tid; j < end; j += 256)
        atomicAdd(&h[(ebuf[j] >> 20) & 255], 1);
    __syncthreads();
    int v = h[tid];                       // degree of node d = b*256+tid
    sc[tid] = v;
    __syncthreads();
    for (int off = 1; off < 256; off <<= 1) {
        int u = (tid >= off) ? sc[tid - off] : 0;
        __syncthreads();
        sc[tid] += u;
        __syncthreads();
    }
    int rowbase = beg + sc[tid] - v;
    cur[tid] = rowbase;
    int d = b * 256 + tid;
    if (d < N) {
        rc[d] = make_int2(rowbase, v);
        dinv[d] = rsqrtf((float)(v + 1));   // +1 self loop
    }
    __syncthreads();
    for (int j = beg + tid; j < end; j += 256) {
        uint32 w = ebuf[j];
        int p = atomicAdd(&cur[(w >> 20) & 255], 1);
        ssrc[p] = (int)(w & 0xFFFFFu);
    }

    // ---- degree counting-sort of this window's 256 nodes -> perm ----
    __syncthreads();
    h[tid] = 0;
    __syncthreads();
    int bin = (v < 255) ? v : 255;
    atomicAdd(&h[bin], 1);
    __syncthreads();
    int vv = h[tid];
    sc[tid] = vv;
    __syncthreads();
    for (int off = 1; off < 256; off <<= 1) {
        int u = (tid >= off) ? sc[tid - off] : 0;
        __syncthreads();
        sc[tid] += u;
        __syncthreads();
    }
    cur[tid] = sc[tid] - vv;              // exclusive prefix per bin
    __syncthreads();
    int p = atomicAdd(&cur[bin], 1);
    perm[b * 256 + p] = d;                // includes padding nodes d >= N
}

// ============ bf16 helpers ============

__device__ __forceinline__ short f2bf(float f) {
    __hip_bfloat16 b = __float2bfloat16(f);
    return __builtin_bit_cast(short, b);
}

__device__ __forceinline__ float bf2f(short s) {
    uint32 u = ((uint32)(unsigned short)s) << 16;
    return __builtin_bit_cast(float, u);
}

__device__ __forceinline__ bf16x8 pack_bf16x8(float4 v0, float4 v1) {
    bf16x8 r;
    r[0] = f2bf(v0.x); r[1] = f2bf(v0.y); r[2] = f2bf(v0.z); r[3] = f2bf(v0.w);
    r[4] = f2bf(v1.x); r[5] = f2bf(v1.y); r[6] = f2bf(v1.z); r[7] = f2bf(v1.w);
    return r;
}

// ============ embed GEMM via MFMA: h = x @ We^T ([N,128] @ [128,64]^T) ============
// Output hA is bf16. Layouts (m89-verified): A[lane&15][(lane>>4)*8+j],
// B[(lane>>4)*8+j][lane&15], D[(lane>>4)*4+r][lane&15].

__global__ __launch_bounds__(256) void k_embed(const float* __restrict__ x,
                                               const float* __restrict__ We,
                                               short* __restrict__ h, int N) {
    int lane = threadIdx.x & 63;
    int w = threadIdx.x >> 6;
    int l15 = lane & 15;
    int lg = lane >> 4;                       // 0..3

    bf16x8 B[4][4];
#pragma unroll
    for (int ct = 0; ct < 4; ++ct) {
        const float* wr = We + (size_t)(ct * 16 + l15) * 128 + lg * 8;
#pragma unroll
        for (int ks = 0; ks < 4; ++ks) {
            float4 v0 = *(const float4*)(wr + ks * 32);
            float4 v1 = *(const float4*)(wr + ks * 32 + 4);
            B[ct][ks] = pack_bf16x8(v0, v1);
        }
    }

    int rowbase = blockIdx.x * 256 + w * 64;

    f32x4 acc[4][4];
#pragma unroll
    for (int rt = 0; rt < 4; ++rt)
#pragma unroll
        for (int ct = 0; ct < 4; ++ct)
            acc[rt][ct] = (f32x4){0.f, 0.f, 0.f, 0.f};

#pragma unroll
    for (int ks = 0; ks < 4; ++ks) {
#pragma unroll
        for (int rt = 0; rt < 4; ++rt) {
            int row = rowbase + rt * 16 + l15;
            row = (row < N) ? row : (N - 1);          // clamp; stores predicated
            const float* xr = x + (size_t)row * 128 + ks * 32 + lg * 8;
            float4 v0 = *(const float4*)xr;
            float4 v1 = *(const float4*)(xr + 4);
            bf16x8 a = pack_bf16x8(v0, v1);
#pragma unroll
            for (int ct = 0; ct < 4; ++ct)
                acc[rt][ct] = __builtin_amdgcn_mfma_f32_16x16x32_bf16(
                    a, B[ct][ks], acc[rt][ct], 0, 0, 0);
        }
    }

#pragma unroll
    for (int rt = 0; rt < 4; ++rt) {
        int row0 = rowbase + rt * 16 + lg * 4;
#pragma unroll
        for (int r = 0; r < 4; ++r) {
            int row = row0 + r;
            if (row < N) {
#pragma unroll
                for (int ct = 0; ct < 4; ++ct)
                    h[(size_t)row * 64 + ct * 16 + l15] = f2bf(acc[rt][ct][r]);
            }
        }
    }
}

// ============ GCN layer GEMM via MFMA (bf16 in, split fp8 tables out) ========
// D = Wg . h^T with h PRE-ACTIVATED bf16 (bias+relu fused into k_agg).
// Output split by feature half into tab0/tab1 (3.2 MB each, fits per-XCD L2).

__global__ __launch_bounds__(256) void k_gcn(const short* __restrict__ hin,
                                             const float* __restrict__ Wg,
                                             const float* __restrict__ dinv,
                                             uint32* __restrict__ tab0,
                                             uint32* __restrict__ tab1, int N) {
    int lane = threadIdx.x & 63;
    int w = threadIdx.x >> 6;
    int l15 = lane & 15, lg = lane >> 4;

    bf16x8 A[4][2];
#pragma unroll
    for (int rt = 0; rt < 4; ++rt) {
        const float* wr = Wg + (size_t)(rt * 16 + l15) * 64 + lg * 8;
#pragma unroll
        for (int ks = 0; ks < 2; ++ks) {
            float4 v0 = *(const float4*)(wr + ks * 32);
            float4 v1 = *(const float4*)(wr + ks * 32 + 4);
            A[rt][ks] = pack_bf16x8(v0, v1);
        }
    }

    int nodebase = blockIdx.x * 256 + w * 64;   // wave: 64 nodes = 4 tiles of 16

#pragma unroll
    for (int nt = 0; nt < 4; ++nt) {
        int node = nodebase + nt * 16 + l15;
        int nodec = (node < N) ? node : (N - 1);
        const short* hr = hin + ((size_t)nodec << 6) + lg * 8;

        bf16x8 Bf0 = *(const bf16x8*)(hr);
        bf16x8 Bf1 = *(const bf16x8*)(hr + 32);

        f32x4 acc[4];
#pragma unroll
        for (int rt = 0; rt < 4; ++rt) acc[rt] = (f32x4){0.f, 0.f, 0.f, 0.f};
#pragma unroll
        for (int rt = 0; rt < 4; ++rt)
            acc[rt] = __builtin_amdgcn_mfma_f32_16x16x32_bf16(A[rt][0], Bf0, acc[rt], 0, 0, 0);
#pragma unroll
        for (int rt = 0; rt < 4; ++rt)
            acc[rt] = __builtin_amdgcn_mfma_f32_16x16x32_bf16(A[rt][1], Bf1, acc[rt], 0, 0, 0);

        float s = dinv[nodec];
        if (node < N) {
#pragma unroll
            for (int rt = 0; rt < 4; ++rt) {
                int u = 0;
                u = __builtin_amdgcn_cvt_pk_fp8_f32(acc[rt][0] * s, acc[rt][1] * s, u, false);
                u = __builtin_amdgcn_cvt_pk_fp8_f32(acc[rt][2] * s, acc[rt][3] * s, u, true);
                uint32* tp = (rt < 2) ? tab0 : tab1;
                tp[(size_t)node * 8 + (rt & 1) * 4 + lg] = u;
            }
        }
    }
}

// ============ fp8 CSR aggregate: merged halves + degree-sorted dsts ==========
// half = blockIdx&1 (XCD table affinity). Groups take dsts from perm[] so the
// 16 dsts of a wave have near-equal degree (maxd ~= deg). Writes stay
// full-line (64 B per dst-half). 16 independent gathers in flight per iter.

__global__ __launch_bounds__(256) void k_agg(const int2* __restrict__ rc,
                                             const int* __restrict__ ssrc,
                                             const float* __restrict__ dinv,
                                             const uint2* __restrict__ tab0,
                                             const uint2* __restrict__ tab1,
                                             const int* __restrict__ perm,
                                             short* __restrict__ hA,
                                             const float* __restrict__ biasl,
                                             int N, int E) {
    int half = blockIdx.x & 1;
    int bb = blockIdx.x >> 1;
    const uint2* tabh = half ? tab1 : tab0;
    int lane = threadIdx.x & 63;
    int wid = threadIdx.x >> 6;
    int q = lane & 3;
    int g = lane >> 2;                          // group 0..15
    int dbase = (bb * 4 + wid) * 16;
    if (dbase >= N) return;

    int pd = perm[dbase + (lane & 15)];         // degree-sorted dst for slot
    int pdc = (pd < N) ? pd : (N - 1);
    int2 r = rc[pdc];
    int beg = __shfl(r.x, g);
    int deg = __shfl(r.y, g);
    int dg = __shfl(pd, g);                     // this group's dst node
    if (dg >= N) deg = 0;

    floatx2 a01 = {0.f, 0.f}, a23 = {0.f, 0.f}, a45 = {0.f, 0.f}, a67 = {0.f, 0.f};
    auto accum = [&](uint2 v) {
        a01 += __builtin_amdgcn_cvt_pk_f32_fp8((int)v.x, false);
        a23 += __builtin_amdgcn_cvt_pk_f32_fp8((int)v.x, true);
        a45 += __builtin_amdgcn_cvt_pk_f32_fp8((int)v.y, false);
        a67 += __builtin_amdgcn_cvt_pk_f32_fp8((int)v.y, true);
    };

    // self loop (each group reads its own dst row once)
    accum(tabh[(size_t)((dg < N) ? dg : N) * 4 + q]);

    int m = deg;
    m = max(m, __shfl_xor(m, 4));
    m = max(m, __shfl_xor(m, 8));
    m = max(m, __shfl_xor(m, 16));
    m = max(m, __shfl_xor(m, 32));
    int maxd = __builtin_amdgcn_readfirstlane(m);

    int base4 = lane & 60;                      // group base lane
    for (int j = 0; j < maxd; j += 16) {
        int i0 = beg + j + q;                   // edges j..j+3 of this group
        int i1 = i0 + 4;
        int i2 = i0 + 8;
        int i3 = i0 + 12;
        int ev0 = ssrc[i0 < E ? i0 : 0];        // ssrc has tail pad; masked below
        int ev1 = ssrc[i1 < E ? i1 : 0];
        int ev2 = ssrc[i2 < E ? i2 : 0];
        int ev3 = ssrc[i3 < E ? i3 : 0];
        int t0  = __shfl(ev0, base4 | 0);
        int t1  = __shfl(ev0, base4 | 1);
        int t2  = __shfl(ev0, base4 | 2);
        int t3  = __shfl(ev0, base4 | 3);
        int t4  = __shfl(ev1, base4 | 0);
        int t5  = __shfl(ev1, base4 | 1);
        int t6  = __shfl(ev1, base4 | 2);
        int t7  = __shfl(ev1, base4 | 3);
        int t8  = __shfl(ev2, base4 | 0);
        int t9  = __shfl(ev2, base4 | 1);
        int ta  = __shfl(ev2, base4 | 2);
        int tb  = __shfl(ev2, base4 | 3);
        int tc  = __shfl(ev3, base4 | 0);
        int td  = __shfl(ev3, base4 | 1);
        int te  = __shfl(ev3, base4 | 2);
        int tf  = __shfl(ev3, base4 | 3);
        t0 = (j +  0 < deg) ? t0 : N;           // sentinel row N = zeros
        t1 = (j +  1 < deg) ? t1 : N;
        t2 = (j +  2 < deg) ? t2 : N;
        t3 = (j +  3 < deg) ? t3 : N;
        t4 = (j +  4 < deg) ? t4 : N;
        t5 = (j +  5 < deg) ? t5 : N;
        t6 = (j +  6 < deg) ? t6 : N;
        t7 = (j +  7 < deg) ? t7 : N;
        t8 = (j +  8 < deg) ? t8 : N;
        t9 = (j +  9 < deg) ? t9 : N;
        ta = (j + 10 < deg) ? ta : N;
        tb = (j + 11 < deg) ? tb : N;
        tc = (j + 12 < deg) ? tc : N;
        td = (j + 13 < deg) ? td : N;
        te = (j + 14 < deg) ? te : N;
        tf = (j + 15 < deg) ? tf : N;
        uint2 v0 = tabh[(size_t)t0 * 4 + q];    // 16 independent gathers in flight
        uint2 v1 = tabh[(size_t)t1 * 4 + q];
        uint2 v2 = tabh[(size_t)t2 * 4 + q];
        uint2 v3 = tabh[(size_t)t3 * 4 + q];
        uint2 v4 = tabh[(size_t)t4 * 4 + q];
        uint2 v5 = tabh[(size_t)t5 * 4 + q];
        uint2 v6 = tabh[(size_t)t6 * 4 + q];
        uint2 v7 = tabh[(size_t)t7 * 4 + q];
        uint2 v8 = tabh[(size_t)t8 * 4 + q];
        uint2 v9 = tabh[(size_t)t9 * 4 + q];
        uint2 va = tabh[(size_t)ta * 4 + q];
        uint2 vb = tabh[(size_t)tb * 4 + q];
        uint2 vc = tabh[(size_t)tc * 4 + q];
        uint2 vd = tabh[(size_t)td * 4 + q];
        uint2 ve = tabh[(size_t)te * 4 + q];
        uint2 vf = tabh[(size_t)tf * 4 + q];
        accum(v0); accum(v1); accum(v2); accum(v3);
        accum(v4); accum(v5); accum(v6); accum(v7);
        accum(v8); accum(v9); accum(va); accum(vb);
        accum(vc); accum(vd); accum(ve); accum(vf);
    }

    if (dg < N) {
        float dd = dinv[dg];
        const float* bias = biasl + half * 32;
        float4 b0 = *(const float4*)(bias + q * 8);
        float4 b1 = *(const float4*)(bias + q * 8 + 4);
        bf16x8 o;
        o[0] = f2bf(fmaxf(fmaf(dd, a01.x, b0.x), 0.f));
        o[1] = f2bf(fmaxf(fmaf(dd, a01.y, b0.y), 0.f));
        o[2] = f2bf(fmaxf(fmaf(dd, a23.x, b0.z), 0.f));
        o[3] = f2bf(fmaxf(fmaf(dd, a23.y, b0.w), 0.f));
        o[4] = f2bf(fmaxf(fmaf(dd, a45.x, b1.x), 0.f));
        o[5] = f2bf(fmaxf(fmaf(dd, a45.y, b1.y), 0.f));
        o[6] = f2bf(fmaxf(fmaf(dd, a67.x, b1.z), 0.f));
        o[7] = f2bf(fmaxf(fmaf(dd, a67.y, b1.w), 0.f));
        __builtin_nontemporal_store(o, (bf16x8*)(hA + (size_t)dg * 64 + half * 32 + q * 8));
    }
}

// ============ centroid distances + pooling via MFMA ============
// hin is pre-activated bf16. c2 computed in-register from the same fp32
// centroid values loaded for the B-frags.

__global__ __launch_bounds__(256) void k_cent(const short* __restrict__ hin,
                                              const float* __restrict__ C,
                                              float* __restrict__ partials, int N) {
    __shared__ float pool4[4][112];
    __shared__ float h2_s[128];
    int tid = threadIdx.x;
    int lane = tid & 63, w = tid >> 6;
    int l15 = lane & 15, lg = lane >> 4;      // lg = 0..3

    bf16x8 B[7][2];
    float c2r[7];
#pragma unroll
    for (int ct = 0; ct < 7; ++ct) {
        int col = ct * 16 + l15;
        float c2p = 0.f;
#pragma unroll
        for (int ks = 0; ks < 2; ++ks) {
            float4 v0 = make_float4(0.f, 0.f, 0.f, 0.f);
            float4 v1 = make_float4(0.f, 0.f, 0.f, 0.f);
            if (col < 100) {
                const float* cr = C + (size_t)col * 64 + ks * 32 + lg * 8;
                v0 = *(const float4*)cr;
                v1 = *(const float4*)(cr + 4);
            }
            B[ct][ks] = pack_bf16x8(v0, v1);
            c2p = fmaf(v0.x, v0.x, c2p); c2p = fmaf(v0.y, v0.y, c2p);
            c2p = fmaf(v0.z, v0.z, c2p); c2p = fmaf(v0.w, v0.w, c2p);
            c2p = fmaf(v1.x, v1.x, c2p); c2p = fmaf(v1.y, v1.y, c2p);
            c2p = fmaf(v1.z, v1.z, c2p); c2p = fmaf(v1.w, v1.w, c2p);
        }
        c2p += __shfl_xor(c2p, 16);
        c2p += __shfl_xor(c2p, 32);
        c2r[ct] = c2p;                         // full ||C[col]||^2, fp32
    }

    int rowbase = blockIdx.x * 128 + w * 32;

    f32x4 acc[2][7];
#pragma unroll
    for (int rt = 0; rt < 2; ++rt)
#pragma unroll
        for (int ct = 0; ct < 7; ++ct)
            acc[rt][ct] = (f32x4){0.f, 0.f, 0.f, 0.f};

#pragma unroll
    for (int rt = 0; rt < 2; ++rt) {
        int row = rowbase + rt * 16 + l15;
        int rowc = (row < N) ? row : (N - 1);     // clamp; excluded from pooling
        const short* hr = hin + ((size_t)rowc << 6) + lg * 8;
        bf16x8 a0 = *(const bf16x8*)(hr);
        bf16x8 a1 = *(const bf16x8*)(hr + 32);

        float h2p = 0.f;
#pragma unroll
        for (int j = 0; j < 8; ++j) {
            float v0 = bf2f(a0[j]);
            float v1 = bf2f(a1[j]);
            h2p = fmaf(v0, v0, h2p);
            h2p = fmaf(v1, v1, h2p);
        }
        h2p += __shfl_xor(h2p, 16);
        h2p += __shfl_xor(h2p, 32);
        if (lg == 0) h2_s[w * 32 + rt * 16 + l15] = h2p;

#pragma unroll
        for (int ct = 0; ct < 7; ++ct)
            acc[rt][ct] = __builtin_amdgcn_mfma_f32_16x16x32_bf16(
                a0, B[ct][0], acc[rt][ct], 0, 0, 0);
#pragma unroll
        for (int ct = 0; ct < 7; ++ct)
            acc[rt][ct] = __builtin_amdgcn_mfma_f32_16x16x32_bf16(
                a1, B[ct][1], acc[rt][ct], 0, 0, 0);
    }

    float S[7] = {0.f, 0.f, 0.f, 0.f, 0.f, 0.f, 0.f};
#pragma unroll
    for (int rt = 0; rt < 2; ++rt) {
#pragma unroll
        for (int r = 0; r < 4; ++r) {
            int row = rowbase + rt * 16 + lg * 4 + r;
            float h2v = h2_s[w * 32 + rt * 16 + lg * 4 + r];
            bool rv = row < N;
#pragma unroll
            for (int ct = 0; ct < 7; ++ct) {
                int col = ct * 16 + l15;
                float G = acc[rt][ct][r];
                float d2 = fmaxf(h2v + c2r[ct] - 2.f * G, 0.f);
                float xx = d2 + 1e-12f;
                float dist = xx * __frsqrt_rn(xx);       // sqrt via rsq, 1 trans op
                S[ct] += (rv && col < 100) ? dist : 0.f;
            }
        }
    }
#pragma unroll
    for (int ct = 0; ct < 7; ++ct) {
        float s = S[ct];
        s += __shfl_xor(s, 16);
        s += __shfl_xor(s, 32);
        if (lg == 0) pool4[w][ct * 16 + l15] = s;   // S[ct]=0 for padded cols
    }
    __syncthreads();
    if (tid < 112) {
        float s = pool4[0][tid] + pool4[1][tid] + pool4[2][tid] + pool4[3][tid];
        partials[(size_t)blockIdx.x * 128 + tid] = s;
    }
}

// ============ output head: reduce partials + apply W_out ============
// 8 groups x 128; 8-wide unrolled strided sum (independent accumulators for MLP).

__global__ __launch_bounds__(1024) void k_out(const float* __restrict__ partials, int nb,
                                              const float* __restrict__ Wout,
                                              const float* __restrict__ bout,
                                              float* __restrict__ out, float invN) {
    __shared__ float ps[8][112];
    int t = threadIdx.x & 127, g = threadIdx.x >> 7;
    if (t < 112) {
        float s0 = 0.f, s1 = 0.f, s2 = 0.f, s3 = 0.f;
        float s4 = 0.f, s5 = 0.f, s6 = 0.f, s7 = 0.f;
        int b = g;
        for (; b + 56 < nb; b += 64) {
            s0 += partials[(size_t)(b     ) * 128 + t];
            s1 += partials[(size_t)(b +  8) * 128 + t];
            s2 += partials[(size_t)(b + 16) * 128 + t];
            s3 += partials[(size_t)(b + 24) * 128 + t];
            s4 += partials[(size_t)(b + 32) * 128 + t];
            s5 += partials[(size_t)(b + 40) * 128 + t];
            s6 += partials[(size_t)(b + 48) * 128 + t];
            s7 += partials[(size_t)(b + 56) * 128 + t];
        }
        for (; b < nb; b += 8) s0 += partials[(size_t)b * 128 + t];
        ps[g][t] = ((s0 + s1) + (s2 + s3)) + ((s4 + s5) + (s6 + s7));
    }
    __syncthreads();
    if (threadIdx.x < 10) {
        int tt = threadIdx.x;
        float s = 0.f;
        for (int k = 0; k < 100; ++k) {
            float p = ps[0][k] + ps[1][k] + ps[2][k] + ps[3][k]
                    + ps[4][k] + ps[5][k] + ps[6][k] + ps[7][k];
            s = fmaf(p, Wout[tt * 100 + k], s);
        }
        out[tt] = s * invN + bout[tt];
    }
}

// ============ launcher ============

extern "C" void kernel_launch(void* const* d_in, const int* in_sizes, int n_in,
                              void* d_out, int out_size, void* d_ws, size_t ws_size,
                              hipStream_t stream) {
    const float* x    = (const float*)d_in[0];
    const int*   ei   = (const int*)d_in[1];
    const float* We   = (const float*)d_in[2];
    const float* Wg   = (const float*)d_in[3];
    const float* bg   = (const float*)d_in[4];
    const float* C    = (const float*)d_in[5];
    const float* Wout = (const float*)d_in[6];
    const float* bout = (const float*)d_in[7];
    float*       out  = (float*)d_out;

    const int N = in_sizes[0] / 128;          // 100000
    const int E = in_sizes[1] / 2;            // 1600000
    const int NBUCK = (N + 255) >> 8;         // 391 dst-buckets
    const int NCH = (E + CHUNK - 1) / CHUNK;  // 391 chunks
    const int NBC = (N + 127) / 128;          // k_cent blocks (782)
    const int NBA = (N + 63) / 64;            // k_agg dst-tiles (1563)

    char* ws = (char*)d_ws;
    size_t off = 0;
    auto alloc = [&](size_t bytes) { void* p = ws + off; off += (bytes + 511) & ~(size_t)511; return p; };
    float*  dinv   = (float*)alloc((size_t)N * 4);
    int2*   rc     = (int2*) alloc((size_t)N * 8);
    int*    perm   = (int*)  alloc((size_t)NBUCK * 256 * 4);
    int*    bcnt   = (int*)  alloc((size_t)NBUCK * NCH * 4);
    int*    bofs   = (int*)  alloc((size_t)NBUCK * NCH * 4);
    int*    btot   = (int*)  alloc((size_t)NBUCK * 4);
    int*    bbase  = (int*)  alloc((size_t)(NBUCK + 1) * 4);
    uint32* ebuf   = (uint32*)alloc((size_t)E * 4);
    int*    ssrc   = (int*)  alloc((size_t)(E + 64) * 4);     // pad for agg reads
    short*  hA     = (short*)alloc((size_t)N * 64 * 2);       // bf16 activations
    uint32* tab0   = (uint32*)alloc((size_t)(N + 1) * 32);    // fp8 feats 0..31 + sentinel
    uint32* tab1   = (uint32*)alloc((size_t)(N + 1) * 32);    // fp8 feats 32..63 + sentinel
    float*  partials = (float*)alloc((size_t)NBC * 128 * 4);

    // bucketed CSR build (no global atomics); k_bscan2 also zeroes sentinels
    k_bhist<<<NCH, 256, 0, stream>>>(ei + E, bcnt, E, NBUCK, NCH);
    k_bscan1<<<NBUCK, 512, 0, stream>>>(bcnt, bofs, btot, NCH);
    k_bscan2<<<1, 512, 0, stream>>>(btot, bbase, NBUCK,
                                    tab0 + (size_t)N * 8, tab1 + (size_t)N * 8);
    k_bscatter<<<NCH, 256, 0, stream>>>(ei, bbase, bofs, ebuf, E, NBUCK, NCH);
    k_bsort<<<NBUCK, 256, 0, stream>>>(ebuf, bbase, ssrc, rc, dinv, perm, N);

    // embed (MFMA bf16 out, 256 rows/block). Layer 0 has no pre-activation.
    k_embed<<<(N + 255) / 256, 256, 0, stream>>>(x, We, hA, N);

    // 3 GCN layers: gemm (bf16 hA -> fp8 tab halves), one merged agg dispatch
    // (half = blockIdx&1 XCD affinity; degree-sorted dsts via perm).
    for (int l = 0; l < 3; ++l) {
        k_gcn<<<(N + 255) / 256, 256, 0, stream>>>(hA, Wg + (size_t)l * 64 * 64,
                                                   dinv, tab0, tab1, N);
        k_agg<<<2 * NBA, 256, 0, stream>>>(rc, ssrc, dinv, (const uint2*)tab0,
                                           (const uint2*)tab1, perm, hA,
                                           bg + (size_t)l * 64, N, E);
    }

    // centroid distances + pooling via MFMA (hA already activated; c2 in-reg)
    k_cent<<<NBC, 256, 0, stream>>>(hA, C, partials, N);

    // head: reduce partials + W_out
    k_out<<<1, 1024, 0, stream>>>(partials, NBC, Wout, bout, out, 1.0f / (float)N);
}

// Round 16
// 307.546 us; speedup vs baseline: 1.0799x; 1.0799x over previous
//
#include <hip/hip_runtime.h>
#include <hip/hip_bf16.h>

typedef unsigned int uint32;
typedef float floatx2 __attribute__((ext_vector_type(2)));
typedef __attribute__((ext_vector_type(8))) short bf16x8;
typedef __attribute__((ext_vector_type(4))) float f32x4;

#define CHUNK 4096   // R13: 391 blocks for bhist/bscatter

// ============ bucketed CSR build (dst>>8 buckets, LDS-atomic sort) ============
// NOTE (R12 lesson): do NOT replace with a direct global-atomic scatter --
// random 4B stores write-allocate full 64B lines (~102 MB write traffic).
// NOTE (R15 lesson): do NOT degree-sort the agg dsts -- perm indirection
// breaks dst-contiguity (coalesced self-loop reads, rc loads, hA writes)
// and costs more than the sentinel slots it saves.

__global__ __launch_bounds__(256) void k_bhist(const int* __restrict__ dst,
                                               int* __restrict__ bcnt,
                                               int E, int NBUCK, int NCH) {
    __shared__ int h[512];
    int c = blockIdx.x, tid = threadIdx.x;
    for (int i = tid; i < NBUCK; i += 256) h[i] = 0;
    __syncthreads();
    int base = c * CHUNK;
#pragma unroll
    for (int k = 0; k < CHUNK / 256; ++k) {
        int e = base + k * 256 + tid;
        if (e < E) atomicAdd(&h[dst[e] >> 8], 1);
    }
    __syncthreads();
    for (int i = tid; i < NBUCK; i += 256) bcnt[(size_t)i * NCH + c] = h[i];
}

// scans NCH (<=512) chunk counts per bucket
__global__ __launch_bounds__(512) void k_bscan1(const int* __restrict__ bcnt,
                                                int* __restrict__ bofs,
                                                int* __restrict__ btot, int NCH) {
    __shared__ int tmp[512];
    int b = blockIdx.x, t = threadIdx.x;
    int v = (t < NCH) ? bcnt[(size_t)b * NCH + t] : 0;
    tmp[t] = v;
    __syncthreads();
    for (int off = 1; off < 512; off <<= 1) {
        int u = (t >= off) ? tmp[t - off] : 0;
        __syncthreads();
        tmp[t] += u;
        __syncthreads();
    }
    if (t < NCH) bofs[(size_t)b * NCH + t] = tmp[t] - v;
    if (t == 511) btot[b] = tmp[511];
}

// also zeroes the fp8 sentinel rows (replaces two hipMemsetAsync dispatches)
__global__ __launch_bounds__(512) void k_bscan2(const int* __restrict__ btot,
                                                int* __restrict__ bbase, int nb,
                                                uint32* __restrict__ sent0,
                                                uint32* __restrict__ sent1) {
    __shared__ int tmp[512];
    int t = threadIdx.x;
    if (t < 8) { sent0[t] = 0; sent1[t] = 0; }
    int v = (t < nb) ? btot[t] : 0;
    tmp[t] = v;
    __syncthreads();
    for (int off = 1; off < 512; off <<= 1) {
        int u = (t >= off) ? tmp[t - off] : 0;
        __syncthreads();
        tmp[t] += u;
        __syncthreads();
    }
    if (t < nb) bbase[t] = tmp[t] - v;
    if (t == nb - 1) bbase[nb] = tmp[t];
}

__global__ __launch_bounds__(256) void k_bscatter(const int* __restrict__ ei,
                                                  const int* __restrict__ bbase,
                                                  const int* __restrict__ bofs,
                                                  uint32* __restrict__ ebuf,
                                                  int E, int NBUCK, int NCH) {
    __shared__ int cur[512];
    int c = blockIdx.x, tid = threadIdx.x;
    for (int i = tid; i < NBUCK; i += 256)
        cur[i] = bbase[i] + bofs[(size_t)i * NCH + c];
    __syncthreads();
    int base = c * CHUNK;
#pragma unroll
    for (int k = 0; k < CHUNK / 256; ++k) {
        int e = base + k * 256 + tid;
        if (e < E) {
            int s = ei[e];
            int d = ei[E + e];
            int p = atomicAdd(&cur[d >> 8], 1);
            ebuf[p] = (uint32)s | ((uint32)(d & 255) << 20);
        }
    }
}

__global__ __launch_bounds__(256) void k_bsort(const uint32* __restrict__ ebuf,
                                               const int* __restrict__ bbase,
                                               int* __restrict__ ssrc,
                                               int2* __restrict__ rc,
                                               float* __restrict__ dinv, int N) {
    __shared__ int h[256];
    __shared__ int sc[256];
    __shared__ int cur[256];
    int b = blockIdx.x, tid = threadIdx.x;
    int beg = bbase[b], end = bbase[b + 1];
    h[tid] = 0;
    __syncthreads();
    for (int j = beg + tid; j < end; j += 256)
        atomicAdd(&h[(ebuf[j] >> 20) & 255], 1);
    __syncthreads();
    int v = h[tid];
    sc[tid] = v;
    __syncthreads();
    for (int off = 1; off < 256; off <<= 1) {
        int u = (tid >= off) ? sc[tid - off] : 0;
        __syncthreads();
        sc[tid] += u;
        __syncthreads();
    }
    int rowbase = beg + sc[tid] - v;
    cur[tid] = rowbase;
    int d = b * 256 + tid;
    if (d < N) {
        rc[d] = make_int2(rowbase, v);
        dinv[d] = rsqrtf((float)(v + 1));   // +1 self loop
    }
    __syncthreads();
    for (int j = beg + tid; j < end; j += 256) {
        uint32 w = ebuf[j];
        int p = atomicAdd(&cur[(w >> 20) & 255], 1);
        ssrc[p] = (int)(w & 0xFFFFFu);
    }
}

// ============ bf16 helpers ============

__device__ __forceinline__ short f2bf(float f) {
    __hip_bfloat16 b = __float2bfloat16(f);
    return __builtin_bit_cast(short, b);
}

__device__ __forceinline__ float bf2f(short s) {
    uint32 u = ((uint32)(unsigned short)s) << 16;
    return __builtin_bit_cast(float, u);
}

__device__ __forceinline__ bf16x8 pack_bf16x8(float4 v0, float4 v1) {
    bf16x8 r;
    r[0] = f2bf(v0.x); r[1] = f2bf(v0.y); r[2] = f2bf(v0.z); r[3] = f2bf(v0.w);
    r[4] = f2bf(v1.x); r[5] = f2bf(v1.y); r[6] = f2bf(v1.z); r[7] = f2bf(v1.w);
    return r;
}

// ============ embed GEMM via MFMA: h = x @ We^T ([N,128] @ [128,64]^T) ============
// Output hA is bf16. Layouts (m89-verified): A[lane&15][(lane>>4)*8+j],
// B[(lane>>4)*8+j][lane&15], D[(lane>>4)*4+r][lane&15].

__global__ __launch_bounds__(256) void k_embed(const float* __restrict__ x,
                                               const float* __restrict__ We,
                                               short* __restrict__ h, int N) {
    int lane = threadIdx.x & 63;
    int w = threadIdx.x >> 6;
    int l15 = lane & 15;
    int lg = lane >> 4;                       // 0..3

    bf16x8 B[4][4];
#pragma unroll
    for (int ct = 0; ct < 4; ++ct) {
        const float* wr = We + (size_t)(ct * 16 + l15) * 128 + lg * 8;
#pragma unroll
        for (int ks = 0; ks < 4; ++ks) {
            float4 v0 = *(const float4*)(wr + ks * 32);
            float4 v1 = *(const float4*)(wr + ks * 32 + 4);
            B[ct][ks] = pack_bf16x8(v0, v1);
        }
    }

    int rowbase = blockIdx.x * 256 + w * 64;

    f32x4 acc[4][4];
#pragma unroll
    for (int rt = 0; rt < 4; ++rt)
#pragma unroll
        for (int ct = 0; ct < 4; ++ct)
            acc[rt][ct] = (f32x4){0.f, 0.f, 0.f, 0.f};

#pragma unroll
    for (int ks = 0; ks < 4; ++ks) {
#pragma unroll
        for (int rt = 0; rt < 4; ++rt) {
            int row = rowbase + rt * 16 + l15;
            row = (row < N) ? row : (N - 1);          // clamp; stores predicated
            const float* xr = x + (size_t)row * 128 + ks * 32 + lg * 8;
            float4 v0 = *(const float4*)xr;
            float4 v1 = *(const float4*)(xr + 4);
            bf16x8 a = pack_bf16x8(v0, v1);
#pragma unroll
            for (int ct = 0; ct < 4; ++ct)
                acc[rt][ct] = __builtin_amdgcn_mfma_f32_16x16x32_bf16(
                    a, B[ct][ks], acc[rt][ct], 0, 0, 0);
        }
    }

#pragma unroll
    for (int rt = 0; rt < 4; ++rt) {
        int row0 = rowbase + rt * 16 + lg * 4;
#pragma unroll
        for (int r = 0; r < 4; ++r) {
            int row = row0 + r;
            if (row < N) {
#pragma unroll
                for (int ct = 0; ct < 4; ++ct)
                    h[(size_t)row * 64 + ct * 16 + l15] = f2bf(acc[rt][ct][r]);
            }
        }
    }
}

// ============ GCN layer GEMM via MFMA (bf16 in, split fp8 tables out) ========
// D = Wg . h^T with h PRE-ACTIVATED bf16 (bias+relu fused into k_agg).
// Output split by feature half into tab0/tab1 (3.2 MB each, fits per-XCD L2).

__global__ __launch_bounds__(256) void k_gcn(const short* __restrict__ hin,
                                             const float* __restrict__ Wg,
                                             const float* __restrict__ dinv,
                                             uint32* __restrict__ tab0,
                                             uint32* __restrict__ tab1, int N) {
    int lane = threadIdx.x & 63;
    int w = threadIdx.x >> 6;
    int l15 = lane & 15, lg = lane >> 4;

    bf16x8 A[4][2];
#pragma unroll
    for (int rt = 0; rt < 4; ++rt) {
        const float* wr = Wg + (size_t)(rt * 16 + l15) * 64 + lg * 8;
#pragma unroll
        for (int ks = 0; ks < 2; ++ks) {
            float4 v0 = *(const float4*)(wr + ks * 32);
            float4 v1 = *(const float4*)(wr + ks * 32 + 4);
            A[rt][ks] = pack_bf16x8(v0, v1);
        }
    }

    int nodebase = blockIdx.x * 256 + w * 64;   // wave: 64 nodes = 4 tiles of 16

#pragma unroll
    for (int nt = 0; nt < 4; ++nt) {
        int node = nodebase + nt * 16 + l15;
        int nodec = (node < N) ? node : (N - 1);
        const short* hr = hin + ((size_t)nodec << 6) + lg * 8;

        bf16x8 Bf0 = *(const bf16x8*)(hr);
        bf16x8 Bf1 = *(const bf16x8*)(hr + 32);

        f32x4 acc[4];
#pragma unroll
        for (int rt = 0; rt < 4; ++rt) acc[rt] = (f32x4){0.f, 0.f, 0.f, 0.f};
#pragma unroll
        for (int rt = 0; rt < 4; ++rt)
            acc[rt] = __builtin_amdgcn_mfma_f32_16x16x32_bf16(A[rt][0], Bf0, acc[rt], 0, 0, 0);
#pragma unroll
        for (int rt = 0; rt < 4; ++rt)
            acc[rt] = __builtin_amdgcn_mfma_f32_16x16x32_bf16(A[rt][1], Bf1, acc[rt], 0, 0, 0);

        float s = dinv[nodec];
        if (node < N) {
#pragma unroll
            for (int rt = 0; rt < 4; ++rt) {
                int u = 0;
                u = __builtin_amdgcn_cvt_pk_fp8_f32(acc[rt][0] * s, acc[rt][1] * s, u, false);
                u = __builtin_amdgcn_cvt_pk_fp8_f32(acc[rt][2] * s, acc[rt][3] * s, u, true);
                uint32* tp = (rt < 2) ? tab0 : tab1;
                tp[(size_t)node * 8 + (rt & 1) * 4 + lg] = u;
            }
        }
    }
}

// ============ fp8 CSR aggregate: BOTH half-passes in one dispatch =============
// half = blockIdx&1: under round-robin block->XCD placement, even blocks land
// on even XCDs -> each XCD touches only one 3.2 MB table (L2-resident;
// performance-only assumption). Each 4-lane group owns ONE dst (contiguous --
// R15 lesson); 16 independent gathers in flight per iter. Epilogue fuses
// bias+relu, stores bf16.

__global__ __launch_bounds__(256) void k_agg(const int2* __restrict__ rc,
                                             const int* __restrict__ ssrc,
                                             const float* __restrict__ dinv,
                                             const uint2* __restrict__ tab0,
                                             const uint2* __restrict__ tab1,
                                             short* __restrict__ hA,
                                             const float* __restrict__ biasl,
                                             int N, int E) {
    int half = blockIdx.x & 1;
    int bb = blockIdx.x >> 1;
    const uint2* tabh = half ? tab1 : tab0;
    int lane = threadIdx.x & 63;
    int wid = threadIdx.x >> 6;
    int q = lane & 3;
    int g = lane >> 2;                          // group 0..15
    int dbase = (bb * 4 + wid) * 16;
    if (dbase >= N) return;

    int2 r = rc[min(dbase + (lane & 15), N - 1)];
    int beg = __shfl(r.x, g);
    int deg = __shfl(r.y, g);
    int dg = dbase + g;
    if (dg >= N) deg = 0;

    floatx2 a01 = {0.f, 0.f}, a23 = {0.f, 0.f}, a45 = {0.f, 0.f}, a67 = {0.f, 0.f};
    auto accum = [&](uint2 v) {
        a01 += __builtin_amdgcn_cvt_pk_f32_fp8((int)v.x, false);
        a23 += __builtin_amdgcn_cvt_pk_f32_fp8((int)v.x, true);
        a45 += __builtin_amdgcn_cvt_pk_f32_fp8((int)v.y, false);
        a67 += __builtin_amdgcn_cvt_pk_f32_fp8((int)v.y, true);
    };

    // self loop (each group reads its own dst row once)
    accum(tabh[(size_t)((dg < N) ? dg : N) * 4 + q]);

    int m = deg;
    m = max(m, __shfl_xor(m, 4));
    m = max(m, __shfl_xor(m, 8));
    m = max(m, __shfl_xor(m, 16));
    m = max(m, __shfl_xor(m, 32));
    int maxd = __builtin_amdgcn_readfirstlane(m);

    int base4 = lane & 60;                      // group base lane
    for (int j = 0; j < maxd; j += 16) {
        int i0 = beg + j + q;                   // edges j..j+3 of this group
        int i1 = i0 + 4;
        int i2 = i0 + 8;
        int i3 = i0 + 12;
        int ev0 = ssrc[i0 < E ? i0 : 0];        // ssrc has tail pad; masked below
        int ev1 = ssrc[i1 < E ? i1 : 0];
        int ev2 = ssrc[i2 < E ? i2 : 0];
        int ev3 = ssrc[i3 < E ? i3 : 0];
        int t0  = __shfl(ev0, base4 | 0);
        int t1  = __shfl(ev0, base4 | 1);
        int t2  = __shfl(ev0, base4 | 2);
        int t3  = __shfl(ev0, base4 | 3);
        int t4  = __shfl(ev1, base4 | 0);
        int t5  = __shfl(ev1, base4 | 1);
        int t6  = __shfl(ev1, base4 | 2);
        int t7  = __shfl(ev1, base4 | 3);
        int t8  = __shfl(ev2, base4 | 0);
        int t9  = __shfl(ev2, base4 | 1);
        int ta  = __shfl(ev2, base4 | 2);
        int tb  = __shfl(ev2, base4 | 3);
        int tc  = __shfl(ev3, base4 | 0);
        int td  = __shfl(ev3, base4 | 1);
        int te  = __shfl(ev3, base4 | 2);
        int tf  = __shfl(ev3, base4 | 3);
        t0 = (j +  0 < deg) ? t0 : N;           // sentinel row N = zeros
        t1 = (j +  1 < deg) ? t1 : N;
        t2 = (j +  2 < deg) ? t2 : N;
        t3 = (j +  3 < deg) ? t3 : N;
        t4 = (j +  4 < deg) ? t4 : N;
        t5 = (j +  5 < deg) ? t5 : N;
        t6 = (j +  6 < deg) ? t6 : N;
        t7 = (j +  7 < deg) ? t7 : N;
        t8 = (j +  8 < deg) ? t8 : N;
        t9 = (j +  9 < deg) ? t9 : N;
        ta = (j + 10 < deg) ? ta : N;
        tb = (j + 11 < deg) ? tb : N;
        tc = (j + 12 < deg) ? tc : N;
        td = (j + 13 < deg) ? td : N;
        te = (j + 14 < deg) ? te : N;
        tf = (j + 15 < deg) ? tf : N;
        uint2 v0 = tabh[(size_t)t0 * 4 + q];    // 16 independent gathers in flight
        uint2 v1 = tabh[(size_t)t1 * 4 + q];
        uint2 v2 = tabh[(size_t)t2 * 4 + q];
        uint2 v3 = tabh[(size_t)t3 * 4 + q];
        uint2 v4 = tabh[(size_t)t4 * 4 + q];
        uint2 v5 = tabh[(size_t)t5 * 4 + q];
        uint2 v6 = tabh[(size_t)t6 * 4 + q];
        uint2 v7 = tabh[(size_t)t7 * 4 + q];
        uint2 v8 = tabh[(size_t)t8 * 4 + q];
        uint2 v9 = tabh[(size_t)t9 * 4 + q];
        uint2 va = tabh[(size_t)ta * 4 + q];
        uint2 vb = tabh[(size_t)tb * 4 + q];
        uint2 vc = tabh[(size_t)tc * 4 + q];
        uint2 vd = tabh[(size_t)td * 4 + q];
        uint2 ve = tabh[(size_t)te * 4 + q];
        uint2 vf = tabh[(size_t)tf * 4 + q];
        accum(v0); accum(v1); accum(v2); accum(v3);
        accum(v4); accum(v5); accum(v6); accum(v7);
        accum(v8); accum(v9); accum(va); accum(vb);
        accum(vc); accum(vd); accum(ve); accum(vf);
    }

    if (dg < N) {
        float dd = dinv[dg];
        const float* bias = biasl + half * 32;
        float4 b0 = *(const float4*)(bias + q * 8);
        float4 b1 = *(const float4*)(bias + q * 8 + 4);
        bf16x8 o;
        o[0] = f2bf(fmaxf(fmaf(dd, a01.x, b0.x), 0.f));
        o[1] = f2bf(fmaxf(fmaf(dd, a01.y, b0.y), 0.f));
        o[2] = f2bf(fmaxf(fmaf(dd, a23.x, b0.z), 0.f));
        o[3] = f2bf(fmaxf(fmaf(dd, a23.y, b0.w), 0.f));
        o[4] = f2bf(fmaxf(fmaf(dd, a45.x, b1.x), 0.f));
        o[5] = f2bf(fmaxf(fmaf(dd, a45.y, b1.y), 0.f));
        o[6] = f2bf(fmaxf(fmaf(dd, a67.x, b1.z), 0.f));
        o[7] = f2bf(fmaxf(fmaf(dd, a67.y, b1.w), 0.f));
        __builtin_nontemporal_store(o, (bf16x8*)(hA + (size_t)dg * 64 + half * 32 + q * 8));
    }
}

// ============ centroid distances + pooling via MFMA ============
// hin is pre-activated bf16. c2 computed in-register from the same fp32
// centroid values loaded for the B-frags.

__global__ __launch_bounds__(256) void k_cent(const short* __restrict__ hin,
                                              const float* __restrict__ C,
                                              float* __restrict__ partials, int N) {
    __shared__ float pool4[4][112];
    __shared__ float h2_s[128];
    int tid = threadIdx.x;
    int lane = tid & 63, w = tid >> 6;
    int l15 = lane & 15, lg = lane >> 4;      // lg = 0..3

    bf16x8 B[7][2];
    float c2r[7];
#pragma unroll
    for (int ct = 0; ct < 7; ++ct) {
        int col = ct * 16 + l15;
        float c2p = 0.f;
#pragma unroll
        for (int ks = 0; ks < 2; ++ks) {
            float4 v0 = make_float4(0.f, 0.f, 0.f, 0.f);
            float4 v1 = make_float4(0.f, 0.f, 0.f, 0.f);
            if (col < 100) {
                const float* cr = C + (size_t)col * 64 + ks * 32 + lg * 8;
                v0 = *(const float4*)cr;
                v1 = *(const float4*)(cr + 4);
            }
            B[ct][ks] = pack_bf16x8(v0, v1);
            c2p = fmaf(v0.x, v0.x, c2p); c2p = fmaf(v0.y, v0.y, c2p);
            c2p = fmaf(v0.z, v0.z, c2p); c2p = fmaf(v0.w, v0.w, c2p);
            c2p = fmaf(v1.x, v1.x, c2p); c2p = fmaf(v1.y, v1.y, c2p);
            c2p = fmaf(v1.z, v1.z, c2p); c2p = fmaf(v1.w, v1.w, c2p);
        }
        c2p += __shfl_xor(c2p, 16);
        c2p += __shfl_xor(c2p, 32);
        c2r[ct] = c2p;                         // full ||C[col]||^2, fp32
    }

    int rowbase = blockIdx.x * 128 + w * 32;

    f32x4 acc[2][7];
#pragma unroll
    for (int rt = 0; rt < 2; ++rt)
#pragma unroll
        for (int ct = 0; ct < 7; ++ct)
            acc[rt][ct] = (f32x4){0.f, 0.f, 0.f, 0.f};

#pragma unroll
    for (int rt = 0; rt < 2; ++rt) {
        int row = rowbase + rt * 16 + l15;
        int rowc = (row < N) ? row : (N - 1);     // clamp; excluded from pooling
        const short* hr = hin + ((size_t)rowc << 6) + lg * 8;
        bf16x8 a0 = *(const bf16x8*)(hr);
        bf16x8 a1 = *(const bf16x8*)(hr + 32);

        float h2p = 0.f;
#pragma unroll
        for (int j = 0; j < 8; ++j) {
            float v0 = bf2f(a0[j]);
            float v1 = bf2f(a1[j]);
            h2p = fmaf(v0, v0, h2p);
            h2p = fmaf(v1, v1, h2p);
        }
        h2p += __shfl_xor(h2p, 16);
        h2p += __shfl_xor(h2p, 32);
        if (lg == 0) h2_s[w * 32 + rt * 16 + l15] = h2p;

#pragma unroll
        for (int ct = 0; ct < 7; ++ct)
            acc[rt][ct] = __builtin_amdgcn_mfma_f32_16x16x32_bf16(
                a0, B[ct][0], acc[rt][ct], 0, 0, 0);
#pragma unroll
        for (int ct = 0; ct < 7; ++ct)
            acc[rt][ct] = __builtin_amdgcn_mfma_f32_16x16x32_bf16(
                a1, B[ct][1], acc[rt][ct], 0, 0, 0);
    }

    float S[7] = {0.f, 0.f, 0.f, 0.f, 0.f, 0.f, 0.f};
#pragma unroll
    for (int rt = 0; rt < 2; ++rt) {
#pragma unroll
        for (int r = 0; r < 4; ++r) {
            int row = rowbase + rt * 16 + lg * 4 + r;
            float h2v = h2_s[w * 32 + rt * 16 + lg * 4 + r];
            bool rv = row < N;
#pragma unroll
            for (int ct = 0; ct < 7; ++ct) {
                int col = ct * 16 + l15;
                float G = acc[rt][ct][r];
                float d2 = fmaxf(h2v + c2r[ct] - 2.f * G, 0.f);
                float xx = d2 + 1e-12f;
                float dist = xx * __frsqrt_rn(xx);       // sqrt via rsq, 1 trans op
                S[ct] += (rv && col < 100) ? dist : 0.f;
            }
        }
    }
#pragma unroll
    for (int ct = 0; ct < 7; ++ct) {
        float s = S[ct];
        s += __shfl_xor(s, 16);
        s += __shfl_xor(s, 32);
        if (lg == 0) pool4[w][ct * 16 + l15] = s;   // S[ct]=0 for padded cols
    }
    __syncthreads();
    if (tid < 112) {
        float s = pool4[0][tid] + pool4[1][tid] + pool4[2][tid] + pool4[3][tid];
        partials[(size_t)blockIdx.x * 128 + tid] = s;
    }
}

// ============ output head: reduce partials + apply W_out ============
// 8 groups x 128; 8-wide unrolled strided sum (independent accumulators for MLP).

__global__ __launch_bounds__(1024) void k_out(const float* __restrict__ partials, int nb,
                                              const float* __restrict__ Wout,
                                              const float* __restrict__ bout,
                                              float* __restrict__ out, float invN) {
    __shared__ float ps[8][112];
    int t = threadIdx.x & 127, g = threadIdx.x >> 7;
    if (t < 112) {
        float s0 = 0.f, s1 = 0.f, s2 = 0.f, s3 = 0.f;
        float s4 = 0.f, s5 = 0.f, s6 = 0.f, s7 = 0.f;
        int b = g;
        for (; b + 56 < nb; b += 64) {
            s0 += partials[(size_t)(b     ) * 128 + t];
            s1 += partials[(size_t)(b +  8) * 128 + t];
            s2 += partials[(size_t)(b + 16) * 128 + t];
            s3 += partials[(size_t)(b + 24) * 128 + t];
            s4 += partials[(size_t)(b + 32) * 128 + t];
            s5 += partials[(size_t)(b + 40) * 128 + t];
            s6 += partials[(size_t)(b + 48) * 128 + t];
            s7 += partials[(size_t)(b + 56) * 128 + t];
        }
        for (; b < nb; b += 8) s0 += partials[(size_t)b * 128 + t];
        ps[g][t] = ((s0 + s1) + (s2 + s3)) + ((s4 + s5) + (s6 + s7));
    }
    __syncthreads();
    if (threadIdx.x < 10) {
        int tt = threadIdx.x;
        float s = 0.f;
        for (int k = 0; k < 100; ++k) {
            float p = ps[0][k] + ps[1][k] + ps[2][k] + ps[3][k]
                    + ps[4][k] + ps[5][k] + ps[6][k] + ps[7][k];
            s = fmaf(p, Wout[tt * 100 + k], s);
        }
        out[tt] = s * invN + bout[tt];
    }
}

// ============ launcher ============

extern "C" void kernel_launch(void* const* d_in, const int* in_sizes, int n_in,
                              void* d_out, int out_size, void* d_ws, size_t ws_size,
                              hipStream_t stream) {
    const float* x    = (const float*)d_in[0];
    const int*   ei   = (const int*)d_in[1];
    const float* We   = (const float*)d_in[2];
    const float* Wg   = (const float*)d_in[3];
    const float* bg   = (const float*)d_in[4];
    const float* C    = (const float*)d_in[5];
    const float* Wout = (const float*)d_in[6];
    const float* bout = (const float*)d_in[7];
    float*       out  = (float*)d_out;

    const int N = in_sizes[0] / 128;          // 100000
    const int E = in_sizes[1] / 2;            // 1600000
    const int NBUCK = (N + 255) >> 8;         // 391 dst-buckets
    const int NCH = (E + CHUNK - 1) / CHUNK;  // 391 chunks
    const int NBC = (N + 127) / 128;          // k_cent blocks (782)
    const int NBA = (N + 63) / 64;            // k_agg dst-tiles (1563)

    char* ws = (char*)d_ws;
    size_t off = 0;
    auto alloc = [&](size_t bytes) { void* p = ws + off; off += (bytes + 511) & ~(size_t)511; return p; };
    float*  dinv   = (float*)alloc((size_t)N * 4);
    int2*   rc     = (int2*) alloc((size_t)N * 8);
    int*    bcnt   = (int*)  alloc((size_t)NBUCK * NCH * 4);
    int*    bofs   = (int*)  alloc((size_t)NBUCK * NCH * 4);
    int*    btot   = (int*)  alloc((size_t)NBUCK * 4);
    int*    bbase  = (int*)  alloc((size_t)(NBUCK + 1) * 4);
    uint32* ebuf   = (uint32*)alloc((size_t)E * 4);
    int*    ssrc   = (int*)  alloc((size_t)(E + 64) * 4);     // pad for agg reads
    short*  hA     = (short*)alloc((size_t)N * 64 * 2);       // bf16 activations
    uint32* tab0   = (uint32*)alloc((size_t)(N + 1) * 32);    // fp8 feats 0..31 + sentinel
    uint32* tab1   = (uint32*)alloc((size_t)(N + 1) * 32);    // fp8 feats 32..63 + sentinel
    float*  partials = (float*)alloc((size_t)NBC * 128 * 4);

    // bucketed CSR build (no global atomics); k_bscan2 also zeroes sentinels
    k_bhist<<<NCH, 256, 0, stream>>>(ei + E, bcnt, E, NBUCK, NCH);
    k_bscan1<<<NBUCK, 512, 0, stream>>>(bcnt, bofs, btot, NCH);
    k_bscan2<<<1, 512, 0, stream>>>(btot, bbase, NBUCK,
                                    tab0 + (size_t)N * 8, tab1 + (size_t)N * 8);
    k_bscatter<<<NCH, 256, 0, stream>>>(ei, bbase, bofs, ebuf, E, NBUCK, NCH);
    k_bsort<<<NBUCK, 256, 0, stream>>>(ebuf, bbase, ssrc, rc, dinv, N);

    // embed (MFMA bf16 out, 256 rows/block). Layer 0 has no pre-activation.
    k_embed<<<(N + 255) / 256, 256, 0, stream>>>(x, We, hA, N);

    // 3 GCN layers: gemm (bf16 hA -> fp8 tab halves), one merged agg dispatch
    // (half = blockIdx&1 -> per-XCD table affinity under round-robin placement).
    for (int l = 0; l < 3; ++l) {
        k_gcn<<<(N + 255) / 256, 256, 0, stream>>>(hA, Wg + (size_t)l * 64 * 64,
                                                   dinv, tab0, tab1, N);
        k_agg<<<2 * NBA, 256, 0, stream>>>(rc, ssrc, dinv, (const uint2*)tab0,
                                           (const uint2*)tab1, hA,
                                           bg + (size_t)l * 64, N, E);
    }

    // centroid distances + pooling via MFMA (hA already activated; c2 in-reg)
    k_cent<<<NBC, 256, 0, stream>>>(hA, C, partials, N);

    // head: reduce partials + W_out
    k_out<<<1, 1024, 0, stream>>>(partials, NBC, Wout, bout, out, 1.0f / (float)N);
}